// Round 3
// baseline (719.036 us; speedup 1.0000x reference)
//
#include <hip/hip_runtime.h>
#include <stdint.h>

typedef unsigned long long u64;
typedef int v4i  __attribute__((ext_vector_type(4)));
typedef int v8i  __attribute__((ext_vector_type(8)));
typedef float v16f __attribute__((ext_vector_type(16)));

#define BATCH 16384
#define IND   768
#define HID   4096
#define NOUT  10
#define EPS   1e-5f

// ---------------------------------------------------------------------------
// 8 sign bits -> dword of 8 fp4(e2m1) nibbles: nibble i = +1 (0x2) if bit i
// clear, -1 (0xA) if set (bit set == negative). Full-rate ops only.
// ---------------------------------------------------------------------------
__device__ __forceinline__ unsigned nib8(unsigned b) {
    unsigned e = ((b & 0x55u) * 0x00208208u) & 0x08080808u;
    unsigned o = (((b >> 1) & 0x55u) * 0x00208208u) & 0x08080808u;
    return 0x22222222u | e | (o << 4);
}

__device__ __forceinline__ void gload16(const v4i* g, v4i* l) {
    __builtin_amdgcn_global_load_lds(
        (const __attribute__((address_space(1))) void*)g,
        (__attribute__((address_space(3))) void*)l, 16, 0, 0);
}

// ---------------------------------------------------------------------------
// Pack sign bits row-major: dst[row][w]. Used for W4 only (final layer).
// ---------------------------------------------------------------------------
__global__ void pack_sign_kernel(const float* __restrict__ src, int ld, int nwords,
                                 int nrows, u64* __restrict__ dst) {
    int gt   = blockIdx.x * blockDim.x + threadIdx.x;
    int wave = gt >> 6;
    int lane = gt & 63;
    if (wave >= nrows) return;
    const float* row = src + (size_t)wave * ld;
    u64* drow = dst + (size_t)wave * nwords;
    for (int w = 0; w < nwords; ++w) {
        float v = row[(w << 6) + lane];
        u64 m = __ballot(v < 0.0f);
        if (lane == 0) drow[w] = m;
    }
}

// ---------------------------------------------------------------------------
// float -> fp4 nibble planes, transposed: dst[(2w+q)][row] 16B chunks,
// plane = K/32. One block per row; 4 waves split words.
// ---------------------------------------------------------------------------
__global__ void pack_nib_t_kernel(const float* __restrict__ src, int ld,
                                  int nwords, int nrows, unsigned* __restrict__ dst) {
    int row  = blockIdx.x;
    int wave = threadIdx.x >> 6, lane = threadIdx.x & 63;
    int nw4  = (nwords + 3) >> 2;
    int wend = (wave + 1) * nw4; if (wend > nwords) wend = nwords;
    const float* r = src + (size_t)row * ld;
    for (int w = wave * nw4; w < wend; ++w) {
        u64 m = __ballot(r[(w << 6) + lane] < 0.0f);
        if (lane < 8) {
            unsigned d = nib8((unsigned)(m >> (8 * lane)) & 0xFFu);
            dst[((size_t)(2 * w + (lane >> 2)) * nrows + row) * 4 + (lane & 3)] = d;
        }
    }
}

// ---------------------------------------------------------------------------
// bit-planes [64][BATCH] (u64) -> fp4 nibble planes [128][BATCH] (16B chunks).
// ---------------------------------------------------------------------------
__global__ void expand_bits_kernel(const u64* __restrict__ src,
                                   v4i* __restrict__ dst) {
    int t = blockIdx.x * blockDim.x + threadIdx.x;
    if (t >= 64 * BATCH) return;
    int w = t >> 14, r = t & (BATCH - 1);
    u64 m = src[((size_t)w << 14) + r];
    v4i o0, o1;
    #pragma unroll
    for (int d = 0; d < 4; ++d) {
        o0[d] = (int)nib8((unsigned)(m >> (8 * d)) & 0xFFu);
        o1[d] = (int)nib8((unsigned)(m >> (32 + 8 * d)) & 0xFFu);
    }
    dst[((size_t)(2 * w) << 14) + r]     = o0;
    dst[((size_t)(2 * w + 1) << 14) + r] = o1;
}

// ---------------------------------------------------------------------------
// Binarized GEMM via MX-FP4 MFMA, LDS-staged A / direct-L2 W.
// Block tile 256x256, 8 waves (2M x 4N), wave tile 128x64 (4x2 of 32x32),
// K-step 128 (4 nibble planes). A staged via global_load_lds (8 KB/step,
// double-buffered, 32 KB LDS); one __syncthreads per K-step absorbs the
// L2-miss latency of the whole step's staging behind 1132 cy/SIMD of MFMA.
// W (XCD-L2-resident panel) loaded direct with 1-step register ping-pong.
// Epilogue: exact f32-int dot -> BN -> ballot (wave-uniform) -> one of
// {nibble planes, bit planes, row-major bits}.
// ---------------------------------------------------------------------------
__global__ __launch_bounds__(512, 2) void bgemm_fp4s(
    const v4i* __restrict__ AN,   // [4*rounds][BATCH] 16B chunks
    int rounds,
    const v4i* __restrict__ WN,   // [4*rounds][HID] 16B chunks
    const float* __restrict__ bias, const float* __restrict__ gam,
    const float* __restrict__ bet,  const float* __restrict__ mu,
    const float* __restrict__ var,
    unsigned* __restrict__ ONIB,  // [128][BATCH] nibble planes, or null
    u64* __restrict__ OT,         // [64][BATCH] bit planes, or null
    u64* __restrict__ ORM)        // [BATCH][64] row-major bits, or null
{
    __shared__ v4i sb[2][4][256];           // [buf][plane][row] A tile

    const int bm = blockIdx.x >> 4, bn = blockIdx.x & 15;
    const int m0 = bm << 8, n0 = bn << 8;
    const int tid = threadIdx.x;
    const int wave = tid >> 6, lane = tid & 63;
    const int wm = wave >> 2, wn = wave & 3;     // 2M x 4N wave grid
    const int l31 = lane & 31, q = lane >> 5;

    v16f acc[4][2];
    #pragma unroll
    for (int a = 0; a < 4; ++a)
        #pragma unroll
        for (int b = 0; b < 2; ++b)
            #pragma unroll
            for (int k = 0; k < 16; ++k) acc[a][b][k] = 0.0f;

    // A staging: wave w stages plane (w>>1), rows 128*(w&1)+{0,64}
    const int spl = wave >> 1, sr0 = (wave & 1) << 7;
    const v4i* gpA = AN + (size_t)spl * BATCH + (m0 + sr0 + lane);
    const size_t cstepA = (size_t)4 * BATCH;

    // W direct: base for (q, col block)
    const v4i* gpW = WN + (size_t)q * HID + (n0 + (wn << 6) + l31);
    const size_t cstepW = (size_t)4 * HID;

    union F { v8i v; v4i h[2]; };
    const v4i z4 = {0, 0, 0, 0};
    const int sc1 = 0x7f7f7f7f;             // e8m0 127 -> 2^0 scales

    // prologue: stage A(0), load W(0)
    gload16(gpA,      &sb[0][spl][sr0]);
    gload16(gpA + 64, &sb[0][spl][sr0 + 64]);
    v4i rw[4], nw[4];                       // [2*ks + tj]
    #pragma unroll
    for (int k4 = 0; k4 < 4; ++k4) {
        rw[k4] = gpW[(size_t)(2 * (k4 >> 1)) * HID + 32 * (k4 & 1)];
        nw[k4] = z4;
    }
    gpA += cstepA; gpW += cstepW;
    __syncthreads();

    int buf = 0;
    for (int c = 0; c < rounds; ++c) {
        if (c + 1 < rounds) {
            gload16(gpA,      &sb[buf ^ 1][spl][sr0]);
            gload16(gpA + 64, &sb[buf ^ 1][spl][sr0 + 64]);
            #pragma unroll
            for (int k4 = 0; k4 < 4; ++k4)
                nw[k4] = gpW[(size_t)(2 * (k4 >> 1)) * HID + 32 * (k4 & 1)];
            gpA += cstepA; gpW += cstepW;
        }
        #pragma unroll
        for (int ks = 0; ks < 2; ++ks) {
            const int pl = 2 * ks + q;
            v4i a4[4];
            #pragma unroll
            for (int ti = 0; ti < 4; ++ti)
                a4[ti] = sb[buf][pl][(wm << 7) + (ti << 5) + l31];
            #pragma unroll
            for (int ti = 0; ti < 4; ++ti) {
                F fa; fa.h[0] = a4[ti]; fa.h[1] = z4;
                #pragma unroll
                for (int tj = 0; tj < 2; ++tj) {
                    F fb; fb.h[0] = rw[2 * ks + tj]; fb.h[1] = z4;
                    acc[ti][tj] = __builtin_amdgcn_mfma_scale_f32_32x32x64_f8f6f4(
                        fa.v, fb.v, acc[ti][tj], 4, 4, 0, sc1, 0, sc1);
                }
            }
        }
        __syncthreads();
        #pragma unroll
        for (int k4 = 0; k4 < 4; ++k4) rw[k4] = nw[k4];
        buf ^= 1;
    }

    // ---------------- epilogue ----------------
    float scj[2], muj[2], bej[2], bij[2];
    #pragma unroll
    for (int tj = 0; tj < 2; ++tj) {
        int col = n0 + (wn << 6) + 32 * tj + l31;
        scj[tj] = gam[col] * rsqrtf(var[col] + EPS);
        muj[tj] = mu[col]; bej[tj] = bet[col]; bij[tj] = bias[col];
    }
    const int pbase = (n0 + (wn << 6)) >> 5;     // first nibble plane
    const int pn    = (n0 + (wn << 6)) >> 6;     // bit plane

    #pragma unroll
    for (int ti = 0; ti < 4; ++ti) {
        #pragma unroll
        for (int reg = 0; reg < 16; ++reg) {
            int rbase = (reg & 3) + 8 * (reg >> 2);
            int rA = m0 + (wm << 7) + (ti << 5) + rbase;   // q=0 rows
            u64 bl[2];
            #pragma unroll
            for (int tj = 0; tj < 2; ++tj) {
                float h = acc[ti][tj][reg] + bij[tj];
                float y = (h - muj[tj]) * scj[tj] + bej[tj];
                bl[tj] = __ballot(y < 0.0f);
            }
            // ballot results are wave-uniform:
            u64 wA = (bl[0] & 0xFFFFFFFFull) | (bl[1] << 32);          // row rA
            u64 wB = (bl[0] >> 32) | (bl[1] & 0xFFFFFFFF00000000ull);  // row rA+4
            if (ONIB && lane < 16) {
                u64 src = (lane < 8) ? wA : wB;
                int row = rA + ((lane < 8) ? 0 : 4);
                int j   = lane & 7;
                unsigned byte = (unsigned)(src >> (8 * j)) & 0xFFu;
                ONIB[((size_t)(pbase + (j >> 2)) * BATCH + row) * 4 + (j & 3)]
                    = nib8(byte);
            }
            if (OT && lane == 0) {
                OT[(size_t)pn * BATCH + rA]     = wA;
                OT[(size_t)pn * BATCH + rA + 4] = wB;
            }
            if (ORM && lane == 0) {
                ORM[(size_t)rA * 64 + pn]       = wA;
                ORM[(size_t)(rA + 4) * 64 + pn] = wB;
            }
        }
    }
}

// ---------------------------------------------------------------------------
// Final layer: N=10, K=4096 (64 words). One wave per row; exact-int dots,
// BN, log_softmax.
// ---------------------------------------------------------------------------
__global__ void final_layer_kernel(
    const u64* __restrict__ Ap,   // [B][64] row-major
    const u64* __restrict__ Wp,   // [10][64] row-major
    const float* __restrict__ bias, const float* __restrict__ gam,
    const float* __restrict__ bet,  const float* __restrict__ mu,
    const float* __restrict__ var,
    float* __restrict__ out)      // [B][10]
{
    int gt   = blockIdx.x * blockDim.x + threadIdx.x;
    int row  = gt >> 6;
    int lane = gt & 63;
    if (row >= BATCH) return;

    u64 a = Ap[(size_t)row * 64 + lane];
    unsigned p[NOUT];
    #pragma unroll
    for (int j = 0; j < NOUT; ++j)
        p[j] = (unsigned)__popcll(a ^ Wp[j * 64 + lane]);

    #pragma unroll
    for (int j = 0; j < NOUT; ++j) {
        #pragma unroll
        for (int off = 32; off >= 1; off >>= 1)
            p[j] += __shfl_xor(p[j], off, 64);
    }

    float z[NOUT];
    float mx = -1e30f;
    #pragma unroll
    for (int j = 0; j < NOUT; ++j) {
        float hh = (float)(HID - 2 * (int)p[j]) + bias[j];
        float sc = gam[j] * rsqrtf(var[j] + EPS);
        z[j] = (hh - mu[j]) * sc + bet[j];
        mx = fmaxf(mx, z[j]);
    }
    float s = 0.0f;
    #pragma unroll
    for (int j = 0; j < NOUT; ++j) s += expf(z[j] - mx);
    float lse = logf(s) + mx;
    if (lane < NOUT) out[(size_t)row * NOUT + lane] = z[lane] - lse;
}

// ---------------------------------------------------------------------------
extern "C" void kernel_launch(void* const* d_in, const int* in_sizes, int n_in,
                              void* d_out, int out_size, void* d_ws, size_t ws_size,
                              hipStream_t stream) {
    (void)in_sizes; (void)n_in; (void)out_size; (void)ws_size;

    const float* x   = (const float*)d_in[0];
    const float* w1  = (const float*)d_in[1];
    const float* b1  = (const float*)d_in[2];
    const float* g1  = (const float*)d_in[3];
    const float* be1 = (const float*)d_in[4];
    const float* m1  = (const float*)d_in[5];
    const float* v1  = (const float*)d_in[6];
    const float* w2  = (const float*)d_in[7];
    const float* b2  = (const float*)d_in[8];
    const float* g2  = (const float*)d_in[9];
    const float* be2 = (const float*)d_in[10];
    const float* m2  = (const float*)d_in[11];
    const float* v2  = (const float*)d_in[12];
    const float* w3  = (const float*)d_in[13];
    const float* b3  = (const float*)d_in[14];
    const float* g3  = (const float*)d_in[15];
    const float* be3 = (const float*)d_in[16];
    const float* m3  = (const float*)d_in[17];
    const float* v3  = (const float*)d_in[18];
    const float* w4  = (const float*)d_in[19];
    const float* b4  = (const float*)d_in[20];
    const float* g4  = (const float*)d_in[21];
    const float* be4 = (const float*)d_in[22];
    const float* m4  = (const float*)d_in[23];
    const float* v4  = (const float*)d_in[24];

    // workspace layout (bytes) — identical footprint to the proven R2 layout:
    //   XN    @ 0        :  6 MB  x nibbles            [24][BATCH]
    //   W1N   @ 6291456  :  1.5MB w1 nibbles           [24][HID]
    //   WBN   @ 7864320  :  8 MB  w2 then w3 nibbles   [128][HID]
    //   ANa   @ 16252928 : 32 MB  A nibbles (L2 in, then L3 in) [128][BATCH]
    //   aBits @ 49807360 :  8 MB  a2 bit planes        [64][BATCH]
    //   a3RM  @ 58195968 :  8 MB  a3 bits row-major    [BATCH][64]
    //   w4p   @ 66584576 :  5 KB
    char* ws = (char*)d_ws;
    unsigned* XN    = (unsigned*)(ws);
    unsigned* W1N   = (unsigned*)(ws + 6291456);
    unsigned* WBN   = (unsigned*)(ws + 7864320);
    unsigned* ANa   = (unsigned*)(ws + 16252928);
    u64*      aBits = (u64*)     (ws + 49807360);
    u64*      a3RM  = (u64*)     (ws + 58195968);
    u64*      w4p   = (u64*)     (ws + 66584576);

    // pack inputs/weights to fp4 nibble planes
    pack_nib_t_kernel<<<BATCH, 256, 0, stream>>>(x, 784, 12, BATCH, XN);
    pack_nib_t_kernel<<<HID, 256, 0, stream>>>(w1, IND, 12, HID, W1N);
    pack_nib_t_kernel<<<HID, 256, 0, stream>>>(w2, HID, 64, HID, WBN);
    pack_sign_kernel<<<3, 256, 0, stream>>>(w4, HID, 64, NOUT, w4p);

    // layer 1: K=768 (6 K-steps) -> nibble planes directly
    bgemm_fp4s<<<1024, 512, 0, stream>>>((const v4i*)XN, 6, (const v4i*)W1N,
                                         b1, g1, be1, m1, v1,
                                         ANa, nullptr, nullptr);
    // layer 2: K=4096 (32 K-steps) -> bit planes (ANa still input here)
    bgemm_fp4s<<<1024, 512, 0, stream>>>((const v4i*)ANa, 32, (const v4i*)WBN,
                                         b2, g2, be2, m2, v2,
                                         nullptr, aBits, nullptr);
    // w3 overwrites w2 (consumed); a2 bits -> nibbles overwrite ANa (consumed)
    pack_nib_t_kernel<<<HID, 256, 0, stream>>>(w3, HID, 64, HID, WBN);
    expand_bits_kernel<<<4096, 256, 0, stream>>>(aBits, (v4i*)ANa);

    // layer 3 -> row-major bits for the final layer
    bgemm_fp4s<<<1024, 512, 0, stream>>>((const v4i*)ANa, 32, (const v4i*)WBN,
                                         b3, g3, be3, m3, v3,
                                         nullptr, nullptr, a3RM);

    // layer 4 + log_softmax
    final_layer_kernel<<<BATCH / 4, 256, 0, stream>>>(a3RM, w4p,
                                                      b4, g4, be4, m4, v4,
                                                      (float*)d_out);
}

// Round 4
// 707.097 us; speedup vs baseline: 1.0169x; 1.0169x over previous
//
#include <hip/hip_runtime.h>
#include <stdint.h>

typedef unsigned long long u64;
typedef int v4i  __attribute__((ext_vector_type(4)));
typedef int v8i  __attribute__((ext_vector_type(8)));
typedef float v16f __attribute__((ext_vector_type(16)));

#define BATCH 16384
#define IND   768
#define HID   4096
#define NOUT  10
#define EPS   1e-5f

// ---------------------------------------------------------------------------
// 8 sign bits -> dword of 8 fp4(e2m1) nibbles: nibble i = +1 (0x2) if bit i
// clear, -1 (0xA) if set (bit set == negative). Full-rate ops only.
// ---------------------------------------------------------------------------
__device__ __forceinline__ unsigned nib8(unsigned b) {
    unsigned e = ((b & 0x55u) * 0x00208208u) & 0x08080808u;
    unsigned o = (((b >> 1) & 0x55u) * 0x00208208u) & 0x08080808u;
    return 0x22222222u | e | (o << 4);
}

__device__ __forceinline__ void gload16(const v4i* g, v4i* l) {
    __builtin_amdgcn_global_load_lds(
        (const __attribute__((address_space(1))) void*)g,
        (__attribute__((address_space(3))) void*)l, 16, 0, 0);
}

// ---------------------------------------------------------------------------
// Pack sign bits row-major: dst[row][w]. Used for W4 only (final layer).
// ---------------------------------------------------------------------------
__global__ void pack_sign_kernel(const float* __restrict__ src, int ld, int nwords,
                                 int nrows, u64* __restrict__ dst) {
    int gt   = blockIdx.x * blockDim.x + threadIdx.x;
    int wave = gt >> 6;
    int lane = gt & 63;
    if (wave >= nrows) return;
    const float* row = src + (size_t)wave * ld;
    u64* drow = dst + (size_t)wave * nwords;
    for (int w = 0; w < nwords; ++w) {
        float v = row[(w << 6) + lane];
        u64 m = __ballot(v < 0.0f);
        if (lane == 0) drow[w] = m;
    }
}

// ---------------------------------------------------------------------------
// float -> fp4 nibble planes, transposed: dst[(2w+q)][row] 16B chunks,
// plane = K/32. One block per row; 4 waves split words.
// ---------------------------------------------------------------------------
__global__ void pack_nib_t_kernel(const float* __restrict__ src, int ld,
                                  int nwords, int nrows, unsigned* __restrict__ dst) {
    int row  = blockIdx.x;
    int wave = threadIdx.x >> 6, lane = threadIdx.x & 63;
    int nw4  = (nwords + 3) >> 2;
    int wend = (wave + 1) * nw4; if (wend > nwords) wend = nwords;
    const float* r = src + (size_t)row * ld;
    for (int w = wave * nw4; w < wend; ++w) {
        u64 m = __ballot(r[(w << 6) + lane] < 0.0f);
        if (lane < 8) {
            unsigned d = nib8((unsigned)(m >> (8 * lane)) & 0xFFu);
            dst[((size_t)(2 * w + (lane >> 2)) * nrows + row) * 4 + (lane & 3)] = d;
        }
    }
}

// ---------------------------------------------------------------------------
// bit-planes [64][BATCH] (u64) -> fp4 nibble planes [128][BATCH] (16B chunks).
// ---------------------------------------------------------------------------
__global__ void expand_bits_kernel(const u64* __restrict__ src,
                                   v4i* __restrict__ dst) {
    int t = blockIdx.x * blockDim.x + threadIdx.x;
    if (t >= 64 * BATCH) return;
    int w = t >> 14, r = t & (BATCH - 1);
    u64 m = src[((size_t)w << 14) + r];
    v4i o0, o1;
    #pragma unroll
    for (int d = 0; d < 4; ++d) {
        o0[d] = (int)nib8((unsigned)(m >> (8 * d)) & 0xFFu);
        o1[d] = (int)nib8((unsigned)(m >> (32 + 8 * d)) & 0xFFu);
    }
    dst[((size_t)(2 * w) << 14) + r]     = o0;
    dst[((size_t)(2 * w + 1) << 14) + r] = o1;
}

// ---------------------------------------------------------------------------
// One K-step (K=128, 4 nibble planes) of the counted-vmcnt pipeline.
// On entry (steady state): stage(c) landing-or-landed, stage(c+1) in flight,
// W(c) in rwU (in flight from last body; compiler-waited before MFMA use).
// vmcnt(6) = stage(c+1) 2 ops + W(c+1)... proves stage(c) complete because
// stage ops precede W ops in each body's issue order.
// ---------------------------------------------------------------------------
__device__ __forceinline__ void kstep(
    int c, int rounds,
    const v4i*& gpA, const v4i*& gpW,
    unsigned& stOff, unsigned& rdOff,
    char* ldsBase, int sOff, unsigned rdBase,
    v4i* rwU, v4i* rwL,
    v16f acc[4][2])
{
    const v4i z4 = {0, 0, 0, 0};
    const int sc1 = 0x7f7f7f7f;                 // e8m0 127 -> 2^0 scales

    asm volatile("s_waitcnt vmcnt(6)" ::: "memory");   // stage(c) landed (mine)
    __builtin_amdgcn_s_barrier();                      // everyone's stage(c) in;
    __builtin_amdgcn_sched_barrier(0);                 // everyone done reading slot

    if (c + 2 < rounds) {                              // stage 2 steps ahead
        gload16(gpA,      (v4i*)(ldsBase + stOff + sOff));
        gload16(gpA + 64, (v4i*)(ldsBase + stOff + sOff + 1024));
        gpA += (size_t)4 * BATCH;
    }
    if (c + 1 < rounds) {                              // W 1 step ahead
        #pragma unroll
        for (int k4 = 0; k4 < 4; ++k4)
            rwL[k4] = gpW[(size_t)(2 * (k4 >> 1)) * HID + 32 * (k4 & 1)];
        gpW += (size_t)4 * HID;
    }

    v4i af0, af1, af2, af3, af4, af5, af6, af7;
    unsigned ra = rdBase + rdOff;
    asm volatile(
        "ds_read_b128 %0, %8 offset:0\n\t"
        "ds_read_b128 %1, %8 offset:512\n\t"
        "ds_read_b128 %2, %8 offset:1024\n\t"
        "ds_read_b128 %3, %8 offset:1536\n\t"
        "ds_read_b128 %4, %8 offset:8192\n\t"
        "ds_read_b128 %5, %8 offset:8704\n\t"
        "ds_read_b128 %6, %8 offset:9216\n\t"
        "ds_read_b128 %7, %8 offset:9728"
        : "=&v"(af0), "=&v"(af1), "=&v"(af2), "=&v"(af3),
          "=&v"(af4), "=&v"(af5), "=&v"(af6), "=&v"(af7)
        : "v"(ra));
    asm volatile("s_waitcnt lgkmcnt(0)" ::: "memory");
    __builtin_amdgcn_sched_barrier(0);                 // rule #18 fence

    union F { v8i v; v4i h[2]; };
    v4i afs[8] = {af0, af1, af2, af3, af4, af5, af6, af7};
    #pragma unroll
    for (int ks = 0; ks < 2; ++ks) {
        #pragma unroll
        for (int ti = 0; ti < 4; ++ti) {
            F fa; fa.h[0] = afs[ks * 4 + ti]; fa.h[1] = z4;
            #pragma unroll
            for (int tj = 0; tj < 2; ++tj) {
                F fb; fb.h[0] = rwU[2 * ks + tj]; fb.h[1] = z4;
                acc[ti][tj] = __builtin_amdgcn_mfma_scale_f32_32x32x64_f8f6f4(
                    fa.v, fb.v, acc[ti][tj], 4, 4, 0, sc1, 0, sc1);
            }
        }
    }
    stOff = (stOff == 32768u) ? 0u : stOff + 16384u;
    rdOff = (rdOff == 32768u) ? 0u : rdOff + 16384u;
}

// ---------------------------------------------------------------------------
// Binarized GEMM via MX-FP4 MFMA, counted-vmcnt pipeline (T3+T4).
// Block tile 256x256, 8 waves (2M x 4N), wave tile 128x64 (4x2 of 32x32),
// K-step 128. A staged via global_load_lds into a 3-deep rotating LDS
// buffer, issued 2 steps ahead; raw s_barrier + manual vmcnt(6) per step —
// the VMEM queue is never drained in the main loop. W direct-from-L2 with
// static rwA/rwB ping-pong (2x unrolled loop, no copies).
// ---------------------------------------------------------------------------
__global__ __launch_bounds__(512, 2) void bgemm_fp4p(
    const v4i* __restrict__ AN,   // [4*rounds][BATCH] 16B chunks
    int rounds,                   // K/128, even
    const v4i* __restrict__ WN,   // [4*rounds][HID] 16B chunks
    const float* __restrict__ bias, const float* __restrict__ gam,
    const float* __restrict__ bet,  const float* __restrict__ mu,
    const float* __restrict__ var,
    unsigned* __restrict__ ONIB,  // [128][BATCH] nibble planes, or null
    u64* __restrict__ OT,         // [64][BATCH] bit planes, or null
    u64* __restrict__ ORM)        // [BATCH][64] row-major bits, or null
{
    __shared__ v4i sb[3][4][256];           // 48 KB: 3-deep x [plane][row]

    const int bm = blockIdx.x >> 4, bn = blockIdx.x & 15;
    const int m0 = bm << 8, n0 = bn << 8;
    const int tid = threadIdx.x;
    const int wave = tid >> 6, lane = tid & 63;
    const int wm = wave >> 2, wn = wave & 3;     // 2M x 4N wave grid
    const int l31 = lane & 31, q = lane >> 5;

    v16f acc[4][2];
    #pragma unroll
    for (int a = 0; a < 4; ++a)
        #pragma unroll
        for (int b = 0; b < 2; ++b)
            #pragma unroll
            for (int k = 0; k < 16; ++k) acc[a][b][k] = 0.0f;

    // A staging: wave w stages plane (w>>1), rows 128*(w&1)+{0,64}
    const int spl = wave >> 1, sr0 = (wave & 1) << 7;
    const v4i* gpA = AN + (size_t)spl * BATCH + (m0 + sr0 + lane);
    const v4i* gpW = WN + (size_t)q * HID + (n0 + (wn << 6) + l31);

    char* ldsBase = (char*)&sb[0][0][0];
    const int sOff = spl * 4096 + (sr0 << 4);
    unsigned rdBase = (unsigned)(q * 4096 + (((wm << 7) + l31) << 4));

    // prologue: stage(0)->buf0, stage(1)->buf1, W(0)->rwA
    gload16(gpA,      (v4i*)(ldsBase + sOff));
    gload16(gpA + 64, (v4i*)(ldsBase + sOff + 1024));
    gpA += (size_t)4 * BATCH;
    gload16(gpA,      (v4i*)(ldsBase + 16384 + sOff));
    gload16(gpA + 64, (v4i*)(ldsBase + 16384 + sOff + 1024));
    gpA += (size_t)4 * BATCH;
    v4i rwA[4], rwB[4];
    #pragma unroll
    for (int k4 = 0; k4 < 4; ++k4)
        rwA[k4] = gpW[(size_t)(2 * (k4 >> 1)) * HID + 32 * (k4 & 1)];
    gpW += (size_t)4 * HID;

    unsigned stOff = 32768u, rdOff = 0u;
    for (int c = 0; c < rounds; c += 2) {
        kstep(c,     rounds, gpA, gpW, stOff, rdOff, ldsBase, sOff, rdBase,
              rwA, rwB, acc);
        kstep(c + 1, rounds, gpA, gpW, stOff, rdOff, ldsBase, sOff, rdBase,
              rwB, rwA, acc);
    }

    // ---------------- epilogue ----------------
    float scj[2], muj[2], bej[2], bij[2];
    #pragma unroll
    for (int tj = 0; tj < 2; ++tj) {
        int col = n0 + (wn << 6) + 32 * tj + l31;
        scj[tj] = gam[col] * rsqrtf(var[col] + EPS);
        muj[tj] = mu[col]; bej[tj] = bet[col]; bij[tj] = bias[col];
    }
    const int pbase = (n0 + (wn << 6)) >> 5;     // first nibble plane
    const int pn    = (n0 + (wn << 6)) >> 6;     // bit plane

    #pragma unroll
    for (int ti = 0; ti < 4; ++ti) {
        #pragma unroll
        for (int reg = 0; reg < 16; ++reg) {
            int rbase = (reg & 3) + 8 * (reg >> 2);
            int rA = m0 + (wm << 7) + (ti << 5) + rbase;   // q=0 rows
            u64 bl[2];
            #pragma unroll
            for (int tj = 0; tj < 2; ++tj) {
                float h = acc[ti][tj][reg] + bij[tj];
                float y = (h - muj[tj]) * scj[tj] + bej[tj];
                bl[tj] = __ballot(y < 0.0f);
            }
            // ballot results are wave-uniform:
            u64 wA = (bl[0] & 0xFFFFFFFFull) | (bl[1] << 32);          // row rA
            u64 wB = (bl[0] >> 32) | (bl[1] & 0xFFFFFFFF00000000ull);  // row rA+4
            if (ONIB && lane < 16) {
                u64 src = (lane < 8) ? wA : wB;
                int row = rA + ((lane < 8) ? 0 : 4);
                int j   = lane & 7;
                unsigned byte = (unsigned)(src >> (8 * j)) & 0xFFu;
                ONIB[((size_t)(pbase + (j >> 2)) * BATCH + row) * 4 + (j & 3)]
                    = nib8(byte);
            }
            if (OT && lane == 0) {
                OT[(size_t)pn * BATCH + rA]     = wA;
                OT[(size_t)pn * BATCH + rA + 4] = wB;
            }
            if (ORM && lane == 0) {
                ORM[(size_t)rA * 64 + pn]       = wA;
                ORM[(size_t)(rA + 4) * 64 + pn] = wB;
            }
        }
    }
}

// ---------------------------------------------------------------------------
// Final layer: N=10, K=4096 (64 words). One wave per row; exact-int dots,
// BN, log_softmax.
// ---------------------------------------------------------------------------
__global__ void final_layer_kernel(
    const u64* __restrict__ Ap,   // [B][64] row-major
    const u64* __restrict__ Wp,   // [10][64] row-major
    const float* __restrict__ bias, const float* __restrict__ gam,
    const float* __restrict__ bet,  const float* __restrict__ mu,
    const float* __restrict__ var,
    float* __restrict__ out)      // [B][10]
{
    int gt   = blockIdx.x * blockDim.x + threadIdx.x;
    int row  = gt >> 6;
    int lane = gt & 63;
    if (row >= BATCH) return;

    u64 a = Ap[(size_t)row * 64 + lane];
    unsigned p[NOUT];
    #pragma unroll
    for (int j = 0; j < NOUT; ++j)
        p[j] = (unsigned)__popcll(a ^ Wp[j * 64 + lane]);

    #pragma unroll
    for (int j = 0; j < NOUT; ++j) {
        #pragma unroll
        for (int off = 32; off >= 1; off >>= 1)
            p[j] += __shfl_xor(p[j], off, 64);
    }

    float z[NOUT];
    float mx = -1e30f;
    #pragma unroll
    for (int j = 0; j < NOUT; ++j) {
        float hh = (float)(HID - 2 * (int)p[j]) + bias[j];
        float sc = gam[j] * rsqrtf(var[j] + EPS);
        z[j] = (hh - mu[j]) * sc + bet[j];
        mx = fmaxf(mx, z[j]);
    }
    float s = 0.0f;
    #pragma unroll
    for (int j = 0; j < NOUT; ++j) s += expf(z[j] - mx);
    float lse = logf(s) + mx;
    if (lane < NOUT) out[(size_t)row * NOUT + lane] = z[lane] - lse;
}

// ---------------------------------------------------------------------------
extern "C" void kernel_launch(void* const* d_in, const int* in_sizes, int n_in,
                              void* d_out, int out_size, void* d_ws, size_t ws_size,
                              hipStream_t stream) {
    (void)in_sizes; (void)n_in; (void)out_size; (void)ws_size;

    const float* x   = (const float*)d_in[0];
    const float* w1  = (const float*)d_in[1];
    const float* b1  = (const float*)d_in[2];
    const float* g1  = (const float*)d_in[3];
    const float* be1 = (const float*)d_in[4];
    const float* m1  = (const float*)d_in[5];
    const float* v1  = (const float*)d_in[6];
    const float* w2  = (const float*)d_in[7];
    const float* b2  = (const float*)d_in[8];
    const float* g2  = (const float*)d_in[9];
    const float* be2 = (const float*)d_in[10];
    const float* m2  = (const float*)d_in[11];
    const float* v2  = (const float*)d_in[12];
    const float* w3  = (const float*)d_in[13];
    const float* b3  = (const float*)d_in[14];
    const float* g3  = (const float*)d_in[15];
    const float* be3 = (const float*)d_in[16];
    const float* m3  = (const float*)d_in[17];
    const float* v3  = (const float*)d_in[18];
    const float* w4  = (const float*)d_in[19];
    const float* b4  = (const float*)d_in[20];
    const float* g4  = (const float*)d_in[21];
    const float* be4 = (const float*)d_in[22];
    const float* m4  = (const float*)d_in[23];
    const float* v4  = (const float*)d_in[24];

    // workspace layout (bytes) — identical to the proven R2/R3 layout:
    //   XN    @ 0        :  6 MB  x nibbles            [24][BATCH]
    //   W1N   @ 6291456  :  1.5MB w1 nibbles           [24][HID]
    //   WBN   @ 7864320  :  8 MB  w2 then w3 nibbles   [128][HID]
    //   ANa   @ 16252928 : 32 MB  A nibbles            [128][BATCH]
    //   aBits @ 49807360 :  8 MB  a2 bit planes        [64][BATCH]
    //   a3RM  @ 58195968 :  8 MB  a3 bits row-major    [BATCH][64]
    //   w4p   @ 66584576 :  5 KB
    char* ws = (char*)d_ws;
    unsigned* XN    = (unsigned*)(ws);
    unsigned* W1N   = (unsigned*)(ws + 6291456);
    unsigned* WBN   = (unsigned*)(ws + 7864320);
    unsigned* ANa   = (unsigned*)(ws + 16252928);
    u64*      aBits = (u64*)     (ws + 49807360);
    u64*      a3RM  = (u64*)     (ws + 58195968);
    u64*      w4p   = (u64*)     (ws + 66584576);

    // pack inputs/weights to fp4 nibble planes
    pack_nib_t_kernel<<<BATCH, 256, 0, stream>>>(x, 784, 12, BATCH, XN);
    pack_nib_t_kernel<<<HID, 256, 0, stream>>>(w1, IND, 12, HID, W1N);
    pack_nib_t_kernel<<<HID, 256, 0, stream>>>(w2, HID, 64, HID, WBN);
    pack_sign_kernel<<<3, 256, 0, stream>>>(w4, HID, 64, NOUT, w4p);

    // layer 1: K=768 (6 K-steps) -> nibble planes directly
    bgemm_fp4p<<<1024, 512, 0, stream>>>((const v4i*)XN, 6, (const v4i*)W1N,
                                         b1, g1, be1, m1, v1,
                                         ANa, nullptr, nullptr);
    // layer 2: K=4096 (32 K-steps) -> bit planes
    bgemm_fp4p<<<1024, 512, 0, stream>>>((const v4i*)ANa, 32, (const v4i*)WBN,
                                         b2, g2, be2, m2, v2,
                                         nullptr, aBits, nullptr);
    // w3 overwrites w2 (consumed); a2 bits -> nibbles overwrite ANa (consumed)
    pack_nib_t_kernel<<<HID, 256, 0, stream>>>(w3, HID, 64, HID, WBN);
    expand_bits_kernel<<<4096, 256, 0, stream>>>(aBits, (v4i*)ANa);

    // layer 3 -> row-major bits for the final layer
    bgemm_fp4p<<<1024, 512, 0, stream>>>((const v4i*)ANa, 32, (const v4i*)WBN,
                                         b3, g3, be3, m3, v3,
                                         nullptr, nullptr, a3RM);

    // layer 4 + log_softmax
    final_layer_kernel<<<BATCH / 4, 256, 0, stream>>>(a3RM, w4p,
                                                      b4, g4, be4, m4, v4,
                                                      (float*)d_out);
}

// Round 5
// 690.773 us; speedup vs baseline: 1.0409x; 1.0236x over previous
//
#include <hip/hip_runtime.h>
#include <stdint.h>

typedef unsigned long long u64;
typedef int v4i  __attribute__((ext_vector_type(4)));
typedef int v8i  __attribute__((ext_vector_type(8)));
typedef float v16f __attribute__((ext_vector_type(16)));

#define BATCH 16384
#define IND   768
#define HID   4096
#define NOUT  10
#define EPS   1e-5f

// ---------------------------------------------------------------------------
// 8 sign bits -> dword of 8 fp4(e2m1) nibbles: nibble i = +1 (0x2) if bit i
// clear, -1 (0xA) if set (bit set == negative). Full-rate ops only.
// ---------------------------------------------------------------------------
__device__ __forceinline__ unsigned nib8(unsigned b) {
    unsigned e = ((b & 0x55u) * 0x00208208u) & 0x08080808u;
    unsigned o = (((b >> 1) & 0x55u) * 0x00208208u) & 0x08080808u;
    return 0x22222222u | e | (o << 4);
}

__device__ __forceinline__ void gload16(const v4i* g, char* l) {
    __builtin_amdgcn_global_load_lds(
        (const __attribute__((address_space(1))) void*)g,
        (__attribute__((address_space(3))) void*)l, 16, 0, 0);
}

// ---------------------------------------------------------------------------
// Pack sign bits row-major: dst[row][w]. Used for W4 only (final layer).
// ---------------------------------------------------------------------------
__global__ void pack_sign_kernel(const float* __restrict__ src, int ld, int nwords,
                                 int nrows, u64* __restrict__ dst) {
    int gt   = blockIdx.x * blockDim.x + threadIdx.x;
    int wave = gt >> 6;
    int lane = gt & 63;
    if (wave >= nrows) return;
    const float* row = src + (size_t)wave * ld;
    u64* drow = dst + (size_t)wave * nwords;
    for (int w = 0; w < nwords; ++w) {
        float v = row[(w << 6) + lane];
        u64 m = __ballot(v < 0.0f);
        if (lane == 0) drow[w] = m;
    }
}

// ---------------------------------------------------------------------------
// float -> fp4 nibble planes, transposed: dst[(2w+q)][row] 16B chunks,
// plane = K/32. One block per row; 4 waves split words.
// ---------------------------------------------------------------------------
__global__ void pack_nib_t_kernel(const float* __restrict__ src, int ld,
                                  int nwords, int nrows, unsigned* __restrict__ dst) {
    int row  = blockIdx.x;
    int wave = threadIdx.x >> 6, lane = threadIdx.x & 63;
    int nw4  = (nwords + 3) >> 2;
    int wend = (wave + 1) * nw4; if (wend > nwords) wend = nwords;
    const float* r = src + (size_t)row * ld;
    for (int w = wave * nw4; w < wend; ++w) {
        u64 m = __ballot(r[(w << 6) + lane] < 0.0f);
        if (lane < 8) {
            unsigned d = nib8((unsigned)(m >> (8 * lane)) & 0xFFu);
            dst[((size_t)(2 * w + (lane >> 2)) * nrows + row) * 4 + (lane & 3)] = d;
        }
    }
}

// ---------------------------------------------------------------------------
// bit-planes [64][BATCH] (u64) -> fp4 nibble planes [128][BATCH] (16B chunks).
// ---------------------------------------------------------------------------
__global__ void expand_bits_kernel(const u64* __restrict__ src,
                                   v4i* __restrict__ dst) {
    int t = blockIdx.x * blockDim.x + threadIdx.x;
    if (t >= 64 * BATCH) return;
    int w = t >> 14, r = t & (BATCH - 1);
    u64 m = src[((size_t)w << 14) + r];
    v4i o0, o1;
    #pragma unroll
    for (int d = 0; d < 4; ++d) {
        o0[d] = (int)nib8((unsigned)(m >> (8 * d)) & 0xFFu);
        o1[d] = (int)nib8((unsigned)(m >> (32 + 8 * d)) & 0xFFu);
    }
    dst[((size_t)(2 * w) << 14) + r]     = o0;
    dst[((size_t)(2 * w + 1) << 14) + r] = o1;
}

// ---------------------------------------------------------------------------
// Binarized GEMM via MX-FP4 MFMA — 8-phase (m201-style) schedule.
// Block tile 256x256, 8 waves (2M x 4N), wave tile 128x64, K-tile 128
// (4 nibble planes). A AND W staged via global_load_lds into a 3-deep
// rotating 32 KB buffer (96 KB LDS total). Per K-tile: 4 phases, one
// C-quadrant (ti) each: {ds_read next frags | issue 1 of 4 gloads for
// tile c+2 | barrier | lgkmcnt(0)+sched_barrier | setprio(1) 4 MFMA
// setprio(0) | barrier}. vmcnt(4) once per tile (never 0 until tail).
// ---------------------------------------------------------------------------
__global__ __launch_bounds__(512, 2) void bgemm_fp4q(
    const v4i* __restrict__ AN,   // [4*rounds][BATCH] 16B chunks
    int rounds,                   // K/128 (>= 3)
    const v4i* __restrict__ WN,   // [4*rounds][HID] 16B chunks
    const float* __restrict__ bias, const float* __restrict__ gam,
    const float* __restrict__ bet,  const float* __restrict__ mu,
    const float* __restrict__ var,
    unsigned* __restrict__ ONIB,  // [128][BATCH] nibble planes, or null
    u64* __restrict__ OT,         // [64][BATCH] bit planes, or null
    u64* __restrict__ ORM)        // [BATCH][64] row-major bits, or null
{
    __shared__ v4i sbuf[6144];              // 96 KB: 3 x {A 16K | W 16K}
    char* lds = (char*)sbuf;

    const int bm = blockIdx.x >> 4, bn = blockIdx.x & 15;
    const int m0 = bm << 8, n0 = bn << 8;
    const int tid = threadIdx.x;
    const int wave = tid >> 6, lane = tid & 63;
    const int wm = wave >> 2, wn = wave & 3;     // 2M x 4N wave grid
    const int l31 = lane & 31, q = lane >> 5;

    v16f acc[4][2];
    #pragma unroll
    for (int a = 0; a < 4; ++a)
        #pragma unroll
        for (int b = 0; b < 2; ++b)
            #pragma unroll
            for (int k = 0; k < 16; ++k) acc[a][b][k] = 0.0f;

    // staging: thread t handles chunk t (planes 0-1) and t+512 (planes 2-3)
    // of both A (16 KB) and W (16 KB) per K-tile.
    const v4i* pA1 = AN + (size_t)(tid >> 8) * BATCH + (m0 + (tid & 255));
    const v4i* pA2 = pA1 + 2 * BATCH;
    const v4i* pW1 = WN + (size_t)(tid >> 8) * HID + (n0 + (tid & 255));
    const v4i* pW2 = pW1 + 2 * HID;
    const unsigned dA1 = (unsigned)(tid << 4);
    const unsigned dA2 = dA1 + 8192u;
    const unsigned dW1 = dA1 + 16384u;
    const unsigned dW2 = dA1 + 24576u;

    // read bases (byte offsets into a 32 KB buffer)
    const unsigned rdA = (unsigned)(q * 4096 + (((wm << 7) + l31) << 4));
    const unsigned rdW = (unsigned)(16384 + q * 4096 + (((wn << 6) + l31) << 4));

    union F { v8i v; v4i h[2]; };
    const v4i z4 = {0, 0, 0, 0};
    const int sc1 = 0x7f7f7f7f;             // e8m0 127 -> 2^0 scales

    // prologue: stage tiles 0 and 1
    #pragma unroll
    for (int t2 = 0; t2 < 2; ++t2) {
        unsigned b = (unsigned)t2 * 32768u;
        gload16(pA1, lds + b + dA1); pA1 += 4 * BATCH;
        gload16(pA2, lds + b + dA2); pA2 += 4 * BATCH;
        gload16(pW1, lds + b + dW1); pW1 += 4 * HID;
        gload16(pW2, lds + b + dW2); pW2 += 4 * HID;
    }
    unsigned rdBuf = 0u, stBuf = 65536u;

    v4i fa0, fa1, fw00, fw01, fw10, fw11;

    for (int c = 0; c < rounds; ++c) {
        const bool st = (c + 2 < rounds);
        // ---------------- phase 0 (ti = 0) ----------------
        if (st) { asm volatile("s_waitcnt vmcnt(4)" ::: "memory"); }
        else    { asm volatile("s_waitcnt vmcnt(0)" ::: "memory"); }
        __builtin_amdgcn_s_barrier();        // tile c resident for all waves
        unsigned aA = rdA + rdBuf;
        unsigned aW = rdW + rdBuf;
        asm volatile("ds_read_b128 %0, %2 offset:0\n\t"
                     "ds_read_b128 %1, %2 offset:8192"
                     : "=&v"(fa0), "=&v"(fa1) : "v"(aA));
        asm volatile("ds_read_b128 %0, %4 offset:0\n\t"
                     "ds_read_b128 %1, %4 offset:512\n\t"
                     "ds_read_b128 %2, %4 offset:8192\n\t"
                     "ds_read_b128 %3, %4 offset:8704"
                     : "=&v"(fw00), "=&v"(fw01), "=&v"(fw10), "=&v"(fw11)
                     : "v"(aW));
        if (st) { gload16(pA1, lds + stBuf + dA1); pA1 += 4 * BATCH; }
        asm volatile("s_waitcnt lgkmcnt(0)" ::: "memory");
        __builtin_amdgcn_sched_barrier(0);
        __builtin_amdgcn_s_setprio(1);
        {
            F a0; a0.h[0] = fa0; a0.h[1] = z4;
            F a1; a1.h[0] = fa1; a1.h[1] = z4;
            F b00; b00.h[0] = fw00; b00.h[1] = z4;
            F b01; b01.h[0] = fw01; b01.h[1] = z4;
            F b10; b10.h[0] = fw10; b10.h[1] = z4;
            F b11; b11.h[0] = fw11; b11.h[1] = z4;
            acc[0][0] = __builtin_amdgcn_mfma_scale_f32_32x32x64_f8f6f4(
                a0.v, b00.v, acc[0][0], 4, 4, 0, sc1, 0, sc1);
            acc[0][1] = __builtin_amdgcn_mfma_scale_f32_32x32x64_f8f6f4(
                a0.v, b01.v, acc[0][1], 4, 4, 0, sc1, 0, sc1);
            acc[0][0] = __builtin_amdgcn_mfma_scale_f32_32x32x64_f8f6f4(
                a1.v, b10.v, acc[0][0], 4, 4, 0, sc1, 0, sc1);
            acc[0][1] = __builtin_amdgcn_mfma_scale_f32_32x32x64_f8f6f4(
                a1.v, b11.v, acc[0][1], 4, 4, 0, sc1, 0, sc1);
        }
        __builtin_amdgcn_s_setprio(0);
        __builtin_amdgcn_s_barrier();
        // ---------------- phases 1-3 (ti = p) ----------------
        #pragma unroll
        for (int p = 1; p < 4; ++p) {
            unsigned aAp = aA + (unsigned)(p * 512);
            asm volatile("ds_read_b128 %0, %2 offset:0\n\t"
                         "ds_read_b128 %1, %2 offset:8192"
                         : "=&v"(fa0), "=&v"(fa1) : "v"(aAp));
            if (st) {
                if (p == 1) { gload16(pA2, lds + stBuf + dA2); pA2 += 4 * BATCH; }
                if (p == 2) { gload16(pW1, lds + stBuf + dW1); pW1 += 4 * HID; }
                if (p == 3) { gload16(pW2, lds + stBuf + dW2); pW2 += 4 * HID; }
            }
            __builtin_amdgcn_s_barrier();
            asm volatile("s_waitcnt lgkmcnt(0)" ::: "memory");
            __builtin_amdgcn_sched_barrier(0);
            __builtin_amdgcn_s_setprio(1);
            {
                F a0; a0.h[0] = fa0; a0.h[1] = z4;
                F a1; a1.h[0] = fa1; a1.h[1] = z4;
                F b00; b00.h[0] = fw00; b00.h[1] = z4;
                F b01; b01.h[0] = fw01; b01.h[1] = z4;
                F b10; b10.h[0] = fw10; b10.h[1] = z4;
                F b11; b11.h[0] = fw11; b11.h[1] = z4;
                acc[p][0] = __builtin_amdgcn_mfma_scale_f32_32x32x64_f8f6f4(
                    a0.v, b00.v, acc[p][0], 4, 4, 0, sc1, 0, sc1);
                acc[p][1] = __builtin_amdgcn_mfma_scale_f32_32x32x64_f8f6f4(
                    a0.v, b01.v, acc[p][1], 4, 4, 0, sc1, 0, sc1);
                acc[p][0] = __builtin_amdgcn_mfma_scale_f32_32x32x64_f8f6f4(
                    a1.v, b10.v, acc[p][0], 4, 4, 0, sc1, 0, sc1);
                acc[p][1] = __builtin_amdgcn_mfma_scale_f32_32x32x64_f8f6f4(
                    a1.v, b11.v, acc[p][1], 4, 4, 0, sc1, 0, sc1);
            }
            __builtin_amdgcn_s_setprio(0);
            __builtin_amdgcn_s_barrier();
        }
        rdBuf = (rdBuf == 65536u) ? 0u : rdBuf + 32768u;
        stBuf = (stBuf == 65536u) ? 0u : stBuf + 32768u;
    }

    // ---------------- epilogue ----------------
    float scj[2], muj[2], bej[2], bij[2];
    #pragma unroll
    for (int tj = 0; tj < 2; ++tj) {
        int col = n0 + (wn << 6) + 32 * tj + l31;
        scj[tj] = gam[col] * rsqrtf(var[col] + EPS);
        muj[tj] = mu[col]; bej[tj] = bet[col]; bij[tj] = bias[col];
    }
    const int pbase = (n0 + (wn << 6)) >> 5;     // first nibble plane
    const int pn    = (n0 + (wn << 6)) >> 6;     // bit plane

    #pragma unroll
    for (int ti = 0; ti < 4; ++ti) {
        #pragma unroll
        for (int reg = 0; reg < 16; ++reg) {
            int rbase = (reg & 3) + 8 * (reg >> 2);
            int rA = m0 + (wm << 7) + (ti << 5) + rbase;   // q=0 rows
            u64 bl[2];
            #pragma unroll
            for (int tj = 0; tj < 2; ++tj) {
                float h = acc[ti][tj][reg] + bij[tj];
                float y = (h - muj[tj]) * scj[tj] + bej[tj];
                bl[tj] = __ballot(y < 0.0f);
            }
            // ballot results are wave-uniform:
            u64 wA = (bl[0] & 0xFFFFFFFFull) | (bl[1] << 32);          // row rA
            u64 wB = (bl[0] >> 32) | (bl[1] & 0xFFFFFFFF00000000ull);  // row rA+4
            if (ONIB && lane < 16) {
                u64 src = (lane < 8) ? wA : wB;
                int row = rA + ((lane < 8) ? 0 : 4);
                int j   = lane & 7;
                unsigned byte = (unsigned)(src >> (8 * j)) & 0xFFu;
                ONIB[((size_t)(pbase + (j >> 2)) * BATCH + row) * 4 + (j & 3)]
                    = nib8(byte);
            }
            if (OT && lane == 0) {
                OT[(size_t)pn * BATCH + rA]     = wA;
                OT[(size_t)pn * BATCH + rA + 4] = wB;
            }
            if (ORM && lane == 0) {
                ORM[(size_t)rA * 64 + pn]       = wA;
                ORM[(size_t)(rA + 4) * 64 + pn] = wB;
            }
        }
    }
}

// ---------------------------------------------------------------------------
// Final layer: N=10, K=4096 (64 words). One wave per row; exact-int dots,
// BN, log_softmax.
// ---------------------------------------------------------------------------
__global__ void final_layer_kernel(
    const u64* __restrict__ Ap,   // [B][64] row-major
    const u64* __restrict__ Wp,   // [10][64] row-major
    const float* __restrict__ bias, const float* __restrict__ gam,
    const float* __restrict__ bet,  const float* __restrict__ mu,
    const float* __restrict__ var,
    float* __restrict__ out)      // [B][10]
{
    int gt   = blockIdx.x * blockDim.x + threadIdx.x;
    int row  = gt >> 6;
    int lane = gt & 63;
    if (row >= BATCH) return;

    u64 a = Ap[(size_t)row * 64 + lane];
    unsigned p[NOUT];
    #pragma unroll
    for (int j = 0; j < NOUT; ++j)
        p[j] = (unsigned)__popcll(a ^ Wp[j * 64 + lane]);

    #pragma unroll
    for (int j = 0; j < NOUT; ++j) {
        #pragma unroll
        for (int off = 32; off >= 1; off >>= 1)
            p[j] += __shfl_xor(p[j], off, 64);
    }

    float z[NOUT];
    float mx = -1e30f;
    #pragma unroll
    for (int j = 0; j < NOUT; ++j) {
        float hh = (float)(HID - 2 * (int)p[j]) + bias[j];
        float sc = gam[j] * rsqrtf(var[j] + EPS);
        z[j] = (hh - mu[j]) * sc + bet[j];
        mx = fmaxf(mx, z[j]);
    }
    float s = 0.0f;
    #pragma unroll
    for (int j = 0; j < NOUT; ++j) s += expf(z[j] - mx);
    float lse = logf(s) + mx;
    if (lane < NOUT) out[(size_t)row * NOUT + lane] = z[lane] - lse;
}

// ---------------------------------------------------------------------------
extern "C" void kernel_launch(void* const* d_in, const int* in_sizes, int n_in,
                              void* d_out, int out_size, void* d_ws, size_t ws_size,
                              hipStream_t stream) {
    (void)in_sizes; (void)n_in; (void)out_size; (void)ws_size;

    const float* x   = (const float*)d_in[0];
    const float* w1  = (const float*)d_in[1];
    const float* b1  = (const float*)d_in[2];
    const float* g1  = (const float*)d_in[3];
    const float* be1 = (const float*)d_in[4];
    const float* m1  = (const float*)d_in[5];
    const float* v1  = (const float*)d_in[6];
    const float* w2  = (const float*)d_in[7];
    const float* b2  = (const float*)d_in[8];
    const float* g2  = (const float*)d_in[9];
    const float* be2 = (const float*)d_in[10];
    const float* m2  = (const float*)d_in[11];
    const float* v2  = (const float*)d_in[12];
    const float* w3  = (const float*)d_in[13];
    const float* b3  = (const float*)d_in[14];
    const float* g3  = (const float*)d_in[15];
    const float* be3 = (const float*)d_in[16];
    const float* m3  = (const float*)d_in[17];
    const float* v3  = (const float*)d_in[18];
    const float* w4  = (const float*)d_in[19];
    const float* b4  = (const float*)d_in[20];
    const float* g4  = (const float*)d_in[21];
    const float* be4 = (const float*)d_in[22];
    const float* m4  = (const float*)d_in[23];
    const float* v4  = (const float*)d_in[24];

    // workspace layout (bytes) — identical to the proven R2/R3/R4 layout:
    //   XN    @ 0        :  6 MB  x nibbles            [24][BATCH]
    //   W1N   @ 6291456  :  1.5MB w1 nibbles           [24][HID]
    //   WBN   @ 7864320  :  8 MB  w2 then w3 nibbles   [128][HID]
    //   ANa   @ 16252928 : 32 MB  A nibbles            [128][BATCH]
    //   aBits @ 49807360 :  8 MB  a2 bit planes        [64][BATCH]
    //   a3RM  @ 58195968 :  8 MB  a3 bits row-major    [BATCH][64]
    //   w4p   @ 66584576 :  5 KB
    char* ws = (char*)d_ws;
    unsigned* XN    = (unsigned*)(ws);
    unsigned* W1N   = (unsigned*)(ws + 6291456);
    unsigned* WBN   = (unsigned*)(ws + 7864320);
    unsigned* ANa   = (unsigned*)(ws + 16252928);
    u64*      aBits = (u64*)     (ws + 49807360);
    u64*      a3RM  = (u64*)     (ws + 58195968);
    u64*      w4p   = (u64*)     (ws + 66584576);

    // pack inputs/weights to fp4 nibble planes
    pack_nib_t_kernel<<<BATCH, 256, 0, stream>>>(x, 784, 12, BATCH, XN);
    pack_nib_t_kernel<<<HID, 256, 0, stream>>>(w1, IND, 12, HID, W1N);
    pack_nib_t_kernel<<<HID, 256, 0, stream>>>(w2, HID, 64, HID, WBN);
    pack_sign_kernel<<<3, 256, 0, stream>>>(w4, HID, 64, NOUT, w4p);

    // layer 1: K=768 (6 K-tiles) -> nibble planes directly
    bgemm_fp4q<<<1024, 512, 0, stream>>>((const v4i*)XN, 6, (const v4i*)W1N,
                                         b1, g1, be1, m1, v1,
                                         ANa, nullptr, nullptr);
    // layer 2: K=4096 (32 K-tiles) -> bit planes
    bgemm_fp4q<<<1024, 512, 0, stream>>>((const v4i*)ANa, 32, (const v4i*)WBN,
                                         b2, g2, be2, m2, v2,
                                         nullptr, aBits, nullptr);
    // w3 overwrites w2 (consumed); a2 bits -> nibbles overwrite ANa (consumed)
    pack_nib_t_kernel<<<HID, 256, 0, stream>>>(w3, HID, 64, HID, WBN);
    expand_bits_kernel<<<4096, 256, 0, stream>>>(aBits, (v4i*)ANa);

    // layer 3 -> row-major bits for the final layer
    bgemm_fp4q<<<1024, 512, 0, stream>>>((const v4i*)ANa, 32, (const v4i*)WBN,
                                         b3, g3, be3, m3, v3,
                                         nullptr, nullptr, a3RM);

    // layer 4 + log_softmax
    final_layer_kernel<<<BATCH / 4, 256, 0, stream>>>(a3RM, w4p,
                                                      b4, g4, be4, m4, v4,
                                                      (float*)d_out);
}

// Round 6
// 675.610 us; speedup vs baseline: 1.0643x; 1.0224x over previous
//
#include <hip/hip_runtime.h>
#include <stdint.h>

typedef unsigned long long u64;
typedef int v4i  __attribute__((ext_vector_type(4)));
typedef int v8i  __attribute__((ext_vector_type(8)));
typedef float v16f __attribute__((ext_vector_type(16)));

#define BATCH 16384
#define IND   768
#define HID   4096
#define NOUT  10
#define EPS   1e-5f

// ---------------------------------------------------------------------------
// 8 sign bits -> dword of 8 fp4(e2m1) nibbles: nibble i = +1 (0x2) if bit i
// clear, -1 (0xA) if set (bit set == negative). Full-rate ops only.
// ---------------------------------------------------------------------------
__device__ __forceinline__ unsigned nib8(unsigned b) {
    unsigned e = ((b & 0x55u) * 0x00208208u) & 0x08080808u;
    unsigned o = (((b >> 1) & 0x55u) * 0x00208208u) & 0x08080808u;
    return 0x22222222u | e | (o << 4);
}

// ---------------------------------------------------------------------------
// Pack sign bits row-major: dst[row][w]. Used for W4 only (final layer).
// ---------------------------------------------------------------------------
__global__ void pack_sign_kernel(const float* __restrict__ src, int ld, int nwords,
                                 int nrows, u64* __restrict__ dst) {
    int gt   = blockIdx.x * blockDim.x + threadIdx.x;
    int wave = gt >> 6;
    int lane = gt & 63;
    if (wave >= nrows) return;
    const float* row = src + (size_t)wave * ld;
    u64* drow = dst + (size_t)wave * nwords;
    for (int w = 0; w < nwords; ++w) {
        float v = row[(w << 6) + lane];
        u64 m = __ballot(v < 0.0f);
        if (lane == 0) drow[w] = m;
    }
}

// ---------------------------------------------------------------------------
// float -> fp4 nibble planes, COALESCED writes: each lane owns one row and a
// 64-column window, builds the two 16B chunks (planes 2w, 2w+1) locally, and
// the wave stores 64 consecutive rows of a plane (1 KB contiguous).
// Reads stream per-lane through L1 (row-sequential); writes fully coalesced.
// Unit u = (rowgroup, w); 4 units per 256-thread block.
// ---------------------------------------------------------------------------
__global__ void pack_nib_rows(const float* __restrict__ src, int ld,
                              int nwords, int nrows, v4i* __restrict__ dst) {
    int u    = blockIdx.x * 4 + (threadIdx.x >> 6);
    int lane = threadIdx.x & 63;
    int rowgrp = u / nwords;
    int w      = u - rowgrp * nwords;
    int row    = (rowgrp << 6) + lane;
    if (row >= nrows) return;
    const float* r = src + (size_t)row * ld + (w << 6);
    #pragma unroll
    for (int half = 0; half < 2; ++half) {
        v4i c;
        #pragma unroll
        for (int d = 0; d < 4; ++d) {
            const float4 f0 = *(const float4*)(r + half * 32 + d * 8);
            const float4 f1 = *(const float4*)(r + half * 32 + d * 8 + 4);
            unsigned b = 0x22222222u;
            b |= (f0.x < 0.f) ? 0x8u        : 0u;
            b |= (f0.y < 0.f) ? 0x80u       : 0u;
            b |= (f0.z < 0.f) ? 0x800u      : 0u;
            b |= (f0.w < 0.f) ? 0x8000u     : 0u;
            b |= (f1.x < 0.f) ? 0x80000u    : 0u;
            b |= (f1.y < 0.f) ? 0x800000u   : 0u;
            b |= (f1.z < 0.f) ? 0x8000000u  : 0u;
            b |= (f1.w < 0.f) ? 0x80000000u : 0u;
            c[d] = (int)b;
        }
        dst[(size_t)(2 * w + half) * nrows + row] = c;
    }
}

// ---------------------------------------------------------------------------
// bit-planes [64][BATCH] (u64) -> fp4 nibble planes [128][BATCH] (16B chunks).
// Fully coalesced both sides.
// ---------------------------------------------------------------------------
__global__ void expand_bits_kernel(const u64* __restrict__ src,
                                   v4i* __restrict__ dst) {
    int t = blockIdx.x * blockDim.x + threadIdx.x;
    if (t >= 64 * BATCH) return;
    int w = t >> 14, r = t & (BATCH - 1);
    u64 m = src[((size_t)w << 14) + r];
    v4i o0, o1;
    #pragma unroll
    for (int d = 0; d < 4; ++d) {
        o0[d] = (int)nib8((unsigned)(m >> (8 * d)) & 0xFFu);
        o1[d] = (int)nib8((unsigned)(m >> (32 + 8 * d)) & 0xFFu);
    }
    dst[((size_t)(2 * w) << 14) + r]     = o0;
    dst[((size_t)(2 * w + 1) << 14) + r] = o1;
}

// ---------------------------------------------------------------------------
// Binarized GEMM via MX-FP4 MFMA — MULTI-BLOCK occupancy design.
// Block tile 128x128, 4 waves (2M x 2N), wave tile 64x64 (2x2 of 32x32),
// acc = 64 f32/lane. K-tile 128 (4 nibble planes). A reg-staged into a
// 16 KB LDS double-buffer (global->reg early, ds_write late); W loaded
// direct-from-L2 into persistent v8i lows (zero uppers, set once).
// __launch_bounds__(256,3): 3 INDEPENDENT blocks/CU (12 waves) — barrier
// drains of one block are hidden by the other two (the m97/m114 mechanism).
// Plain compiler-scheduled C++ K-loop: no inline asm anywhere.
// ---------------------------------------------------------------------------
__global__ __launch_bounds__(256, 3) void bgemm_fp4m(
    const v4i* __restrict__ AN,   // [4*rounds][BATCH] 16B chunks
    int rounds,                   // K/128
    const v4i* __restrict__ WN,   // [4*rounds][HID] 16B chunks
    const float* __restrict__ bias, const float* __restrict__ gam,
    const float* __restrict__ bet,  const float* __restrict__ mu,
    const float* __restrict__ var,
    u64* __restrict__ OT,         // [64][BATCH] bit planes
    u64* __restrict__ ORM)        // [BATCH][64] row-major bits, or null
{
    __shared__ v4i sb[1024];                // 16 KB: 2 x [plane(4)][row(128)]
    char* lds = (char*)sb;

    const int bm = blockIdx.x >> 5, bn = blockIdx.x & 31;
    const int m0 = bm << 7, n0 = bn << 7;
    const int tid = threadIdx.x;
    const int wave = tid >> 6, lane = tid & 63;
    const int wm = wave >> 1, wn = wave & 1;     // 2M x 2N wave grid
    const int l31 = lane & 31, q = lane >> 5;

    v16f acc[2][2];
    #pragma unroll
    for (int a = 0; a < 2; ++a)
        #pragma unroll
        for (int b = 0; b < 2; ++b)
            #pragma unroll
            for (int k = 0; k < 16; ++k) acc[a][b][k] = 0.0f;

    // staging: thread t owns chunks t (plane t>>7, row t&127) and t+256
    const v4i* pA1 = AN + (size_t)(tid >> 7) * BATCH + (m0 + (tid & 127));
    const v4i* pA2 = pA1 + 2 * BATCH;
    const unsigned dA1 = (unsigned)(tid << 4);
    const unsigned dA2 = dA1 + 4096u;

    // W: lane (l31,q), cols n0 + wn*64 + 32*tj + l31, plane 4c+2ks+q
    const v4i* gpW = WN + (size_t)q * HID + (n0 + (wn << 6) + l31);

    // A-frag read base: plane (2ks+q)*2048 + (wm*64 + ti*32 + l31)*16
    const unsigned rdA = (unsigned)(q * 2048 + (((wm << 6) + l31) << 4));

    const v8i z8 = {0, 0, 0, 0, 0, 0, 0, 0};
    v8i wv[4] = {z8, z8, z8, z8};           // [2*ks + tj], uppers stay zero
    v8i av = z8;                            // A frag, upper stays zero
    const int sc1 = 0x7f7f7f7f;             // e8m0 127 -> 2^0 scales

    // prologue: stage tile 0 -> buf 0
    {
        v4i s1 = *pA1, s2 = *pA2;
        pA1 += 4 * BATCH; pA2 += 4 * BATCH;
        *(v4i*)(lds + dA1) = s1;
        *(v4i*)(lds + dA2) = s2;
    }
    __syncthreads();

    unsigned buf = 0;
    for (int c = 0; c < rounds; ++c) {
        // issue next tile's global loads early (latency hides under MFMAs)
        v4i s1, s2;
        const bool st = (c + 1 < rounds);
        if (st) {
            s1 = *pA1; s2 = *pA2;
            pA1 += 4 * BATCH; pA2 += 4 * BATCH;
        }
        // W for this K-tile, straight into persistent v8i lows
        #pragma unroll
        for (int k4 = 0; k4 < 4; ++k4)
            *(v4i*)&wv[k4] = gpW[(size_t)(2 * (k4 >> 1)) * HID + 32 * (k4 & 1)];
        gpW += 4 * HID;

        const char* rb = lds + buf + rdA;
        #pragma unroll
        for (int ks = 0; ks < 2; ++ks)
            #pragma unroll
            for (int ti = 0; ti < 2; ++ti) {
                *(v4i*)&av = *(const v4i*)(rb + ks * 4096 + ti * 512);
                acc[ti][0] = __builtin_amdgcn_mfma_scale_f32_32x32x64_f8f6f4(
                    av, wv[2 * ks + 0], acc[ti][0], 4, 4, 0, sc1, 0, sc1);
                acc[ti][1] = __builtin_amdgcn_mfma_scale_f32_32x32x64_f8f6f4(
                    av, wv[2 * ks + 1], acc[ti][1], 4, 4, 0, sc1, 0, sc1);
            }

        // write staged tile into the other buffer (after all reads of buf)
        if (st) {
            *(v4i*)(lds + (buf ^ 8192u) + dA1) = s1;
            *(v4i*)(lds + (buf ^ 8192u) + dA2) = s2;
        }
        __syncthreads();
        buf ^= 8192u;
    }

    // ---------------- epilogue: exact dot -> BN -> ballot sign-pack --------
    float scj[2], muj[2], bej[2], bij[2];
    #pragma unroll
    for (int tj = 0; tj < 2; ++tj) {
        int col = n0 + (wn << 6) + 32 * tj + l31;
        scj[tj] = gam[col] * rsqrtf(var[col] + EPS);
        muj[tj] = mu[col]; bej[tj] = bet[col]; bij[tj] = bias[col];
    }
    const int pn = ((n0 + (wn << 6)) >> 6);      // output bit plane
    u64* outp = OT + (size_t)pn * BATCH;

    #pragma unroll
    for (int ti = 0; ti < 2; ++ti) {
        #pragma unroll
        for (int reg = 0; reg < 16; ++reg) {
            int rbase = (reg & 3) + 8 * (reg >> 2);
            int rA = m0 + (wm << 6) + (ti << 5) + rbase;   // q=0 rows
            u64 bl[2];
            #pragma unroll
            for (int tj = 0; tj < 2; ++tj) {
                float h = acc[ti][tj][reg] + bij[tj];
                float y = (h - muj[tj]) * scj[tj] + bej[tj];
                bl[tj] = __ballot(y < 0.0f);
            }
            u64 wA = (bl[0] & 0xFFFFFFFFull) | (bl[1] << 32);          // row rA
            u64 wB = (bl[0] >> 32) | (bl[1] & 0xFFFFFFFF00000000ull);  // row rA+4
            if (lane == 0) {
                outp[rA]     = wA;
                outp[rA + 4] = wB;
                if (ORM) {
                    ORM[(size_t)rA * 64 + pn]       = wA;
                    ORM[(size_t)(rA + 4) * 64 + pn] = wB;
                }
            }
        }
    }
}

// ---------------------------------------------------------------------------
// Final layer: N=10, K=4096 (64 words). One wave per row; exact-int dots,
// BN, log_softmax.
// ---------------------------------------------------------------------------
__global__ void final_layer_kernel(
    const u64* __restrict__ Ap,   // [B][64] row-major
    const u64* __restrict__ Wp,   // [10][64] row-major
    const float* __restrict__ bias, const float* __restrict__ gam,
    const float* __restrict__ bet,  const float* __restrict__ mu,
    const float* __restrict__ var,
    float* __restrict__ out)      // [B][10]
{
    int gt   = blockIdx.x * blockDim.x + threadIdx.x;
    int row  = gt >> 6;
    int lane = gt & 63;
    if (row >= BATCH) return;

    u64 a = Ap[(size_t)row * 64 + lane];
    unsigned p[NOUT];
    #pragma unroll
    for (int j = 0; j < NOUT; ++j)
        p[j] = (unsigned)__popcll(a ^ Wp[j * 64 + lane]);

    #pragma unroll
    for (int j = 0; j < NOUT; ++j) {
        #pragma unroll
        for (int off = 32; off >= 1; off >>= 1)
            p[j] += __shfl_xor(p[j], off, 64);
    }

    float z[NOUT];
    float mx = -1e30f;
    #pragma unroll
    for (int j = 0; j < NOUT; ++j) {
        float hh = (float)(HID - 2 * (int)p[j]) + bias[j];
        float sc = gam[j] * rsqrtf(var[j] + EPS);
        z[j] = (hh - mu[j]) * sc + bet[j];
        mx = fmaxf(mx, z[j]);
    }
    float s = 0.0f;
    #pragma unroll
    for (int j = 0; j < NOUT; ++j) s += expf(z[j] - mx);
    float lse = logf(s) + mx;
    if (lane < NOUT) out[(size_t)row * NOUT + lane] = z[lane] - lse;
}

// ---------------------------------------------------------------------------
extern "C" void kernel_launch(void* const* d_in, const int* in_sizes, int n_in,
                              void* d_out, int out_size, void* d_ws, size_t ws_size,
                              hipStream_t stream) {
    (void)in_sizes; (void)n_in; (void)out_size; (void)ws_size;

    const float* x   = (const float*)d_in[0];
    const float* w1  = (const float*)d_in[1];
    const float* b1  = (const float*)d_in[2];
    const float* g1  = (const float*)d_in[3];
    const float* be1 = (const float*)d_in[4];
    const float* m1  = (const float*)d_in[5];
    const float* v1  = (const float*)d_in[6];
    const float* w2  = (const float*)d_in[7];
    const float* b2  = (const float*)d_in[8];
    const float* g2  = (const float*)d_in[9];
    const float* be2 = (const float*)d_in[10];
    const float* m2  = (const float*)d_in[11];
    const float* v2  = (const float*)d_in[12];
    const float* w3  = (const float*)d_in[13];
    const float* b3  = (const float*)d_in[14];
    const float* g3  = (const float*)d_in[15];
    const float* be3 = (const float*)d_in[16];
    const float* m3  = (const float*)d_in[17];
    const float* v3  = (const float*)d_in[18];
    const float* w4  = (const float*)d_in[19];
    const float* b4  = (const float*)d_in[20];
    const float* g4  = (const float*)d_in[21];
    const float* be4 = (const float*)d_in[22];
    const float* m4  = (const float*)d_in[23];
    const float* v4  = (const float*)d_in[24];

    // workspace layout (bytes) — identical to the proven R2-R5 layout:
    //   XN    @ 0        :  6 MB  x nibbles            [24][BATCH]
    //   W1N   @ 6291456  :  1.5MB w1 nibbles           [24][HID]
    //   WBN   @ 7864320  :  8 MB  w2 then w3 nibbles   [128][HID]
    //   ANa   @ 16252928 : 32 MB  A nibbles            [128][BATCH]
    //   aBits @ 49807360 :  8 MB  a1/a2/a3 bit planes  [64][BATCH]
    //   a3RM  @ 58195968 :  8 MB  a3 bits row-major    [BATCH][64]
    //   w4p   @ 66584576 :  5 KB
    char* ws = (char*)d_ws;
    v4i*      XN    = (v4i*)(ws);
    v4i*      W1N   = (v4i*)(ws + 6291456);
    v4i*      WBN   = (v4i*)(ws + 7864320);
    v4i*      ANa   = (v4i*)(ws + 16252928);
    u64*      aBits = (u64*)(ws + 49807360);
    u64*      a3RM  = (u64*)(ws + 58195968);
    u64*      w4p   = (u64*)(ws + 66584576);

    // pack inputs/weights to fp4 nibble planes (coalesced writers)
    pack_nib_rows<<<768,  256, 0, stream>>>(x, 784, 12, BATCH, XN);   // 3072 units
    pack_nib_rows<<<192,  256, 0, stream>>>(w1, IND, 12, HID, W1N);   // 768 units
    pack_nib_rows<<<1024, 256, 0, stream>>>(w2, HID, 64, HID, WBN);   // 4096 units
    pack_sign_kernel<<<3, 256, 0, stream>>>(w4, HID, 64, NOUT, w4p);

    // layer 1: K=768 (6 K-tiles) -> bit planes, then expand (coalesced)
    bgemm_fp4m<<<4096, 256, 0, stream>>>(XN, 6, W1N,
                                         b1, g1, be1, m1, v1, aBits, nullptr);
    expand_bits_kernel<<<4096, 256, 0, stream>>>(aBits, ANa);

    // layer 2: K=4096 (32 K-tiles) -> bit planes
    bgemm_fp4m<<<4096, 256, 0, stream>>>(ANa, 32, WBN,
                                         b2, g2, be2, m2, v2, aBits, nullptr);
    // w3 overwrites w2 (consumed); a2 bits -> nibbles overwrite ANa (consumed)
    pack_nib_rows<<<1024, 256, 0, stream>>>(w3, HID, 64, HID, WBN);
    expand_bits_kernel<<<4096, 256, 0, stream>>>(aBits, ANa);

    // layer 3 -> bit planes (aBits reused) + row-major bits for final layer
    bgemm_fp4m<<<4096, 256, 0, stream>>>(ANa, 32, WBN,
                                         b3, g3, be3, m3, v3, aBits, a3RM);

    // layer 4 + log_softmax
    final_layer_kernel<<<BATCH / 4, 256, 0, stream>>>(a3RM, w4p,
                                                      b4, g4, be4, m4, v4,
                                                      (float*)d_out);
}